// Round 1
// baseline (1564.895 us; speedup 1.0000x reference)
//
#include <hip/hip_runtime.h>
#include <hip/hip_bf16.h>
#include <math.h>

typedef __bf16 bf16x8 __attribute__((ext_vector_type(8)));
typedef float  f32x4  __attribute__((ext_vector_type(4)));

#define DEV static __device__ __forceinline__

DEV unsigned short f2bf(float f) {
    unsigned u = __builtin_bit_cast(unsigned, f);
    u += 0x7fffu + ((u >> 16) & 1u);     // RNE
    return (unsigned short)(u >> 16);
}

// ---------------- fp32 -> bf16 weight convert ----------------
__global__ void k_cvt(const float* __restrict__ in, unsigned short* __restrict__ out) {
    int i = (blockIdx.x * 256 + threadIdx.x) * 4;
    float4 v = *(const float4*)(in + i);
    ushort4 o;
    o.x = f2bf(v.x); o.y = f2bf(v.y); o.z = f2bf(v.z); o.w = f2bf(v.w);
    *(ushort4*)(out + i) = o;
}

// ---------------- adaLN: ada = silu(c) @ Wada^T + bada ----------------
// grid (8, 6144/4), block 256 (4 waves, one output col per wave)
__global__ void k_ada(const float* __restrict__ c, const float* __restrict__ Wada,
                      const float* __restrict__ bada, float* __restrict__ ada) {
    __shared__ float sc[1024];
    int b = blockIdx.x;
    int tid = threadIdx.x;
    for (int k = tid; k < 1024; k += 256) {
        float x = c[b * 1024 + k];
        sc[k] = x / (1.f + __expf(-x));
    }
    __syncthreads();
    int wid = tid >> 6, lane = tid & 63;
    int n = blockIdx.y * 4 + wid;
    const float* wr = Wada + (size_t)n * 1024;
    float acc = 0.f;
    #pragma unroll
    for (int k = 0; k < 1024; k += 64) acc += sc[k + lane] * wr[k + lane];
    #pragma unroll
    for (int o = 32; o; o >>= 1) acc += __shfl_xor(acc, o);
    if (lane == 0) ada[b * 6144 + n] = acc + bada[n];
}

// ---------------- fused rmsnorm + modulate -> bf16 ----------------
// grid 8192 (one row), block 256 (each thread 4 elems)
__global__ void k_norm_mod(const float* __restrict__ x, const float* __restrict__ ada,
                           const float* __restrict__ g, unsigned short* __restrict__ h,
                           int shift_off, int scale_off) {
    int row = blockIdx.x;
    int b = row >> 10;
    int tid = threadIdx.x;
    float4 v = *(const float4*)(x + (size_t)row * 1024 + tid * 4);
    float ss = v.x * v.x + v.y * v.y + v.z * v.z + v.w * v.w;
    #pragma unroll
    for (int o = 32; o; o >>= 1) ss += __shfl_xor(ss, o);
    __shared__ float red[4];
    int wid = tid >> 6, lane = tid & 63;
    if (lane == 0) red[wid] = ss;
    __syncthreads();
    float nrm = sqrtf(red[0] + red[1] + red[2] + red[3]);
    float f = g[0] * 32.f / fmaxf(nrm, 1e-12f);
    float4 s4 = *(const float4*)(ada + b * 6144 + scale_off + tid * 4);
    float4 h4 = *(const float4*)(ada + b * 6144 + shift_off + tid * 4);
    ushort4 o;
    o.x = f2bf(v.x * f * (1.f + s4.x) + h4.x);
    o.y = f2bf(v.y * f * (1.f + s4.y) + h4.y);
    o.z = f2bf(v.z * f * (1.f + s4.z) + h4.z);
    o.w = f2bf(v.w * f * (1.f + s4.w) + h4.w);
    *(ushort4*)(h + (size_t)row * 1024 + tid * 4) = o;
}

// ---------------- bf16 GEMM: C[m,n] = sum_k A[m,k]*B[n,k] (+epilogue) ----------------
// 128x128 tile, 4 waves (2x2 of 64x64), BK=32, mfma_f32_16x16x32_bf16
// EPI: 0 = +bias -> fp32 (qkv)
//      1 = resid + gate*( +bias )         -> fp32 (proj -> x1)
//      2 = gelu_tanh( +bias )             -> bf16 (fc1)
//      3 = resid + gate*( +bias )         -> fp32 (fc2 -> out)
template <int EPI>
__global__ __launch_bounds__(256)
void k_gemm(const unsigned short* __restrict__ A, const unsigned short* __restrict__ Bw,
            const float* __restrict__ bias, int N, int K,
            float* __restrict__ outF, unsigned short* __restrict__ outH,
            const float* __restrict__ resid, const float* __restrict__ ada, int gate_off) {
    __shared__ unsigned short lA[128 * 32];
    __shared__ unsigned short lB[128 * 32];
    int tid = threadIdx.x;
    int m0 = blockIdx.x * 128, n0 = blockIdx.y * 128;
    int wid = tid >> 6, lane = tid & 63;
    int wr = (wid >> 1) * 64, wc = (wid & 1) * 64;
    f32x4 acc[4][4] = {};

    for (int kk = 0; kk < K; kk += 32) {
        #pragma unroll
        for (int r = 0; r < 2; ++r) {
            int f = r * 4096 + tid * 16;            // byte index into the 8KB tile
            int row = f >> 6;                        // 64 B per row (32 bf16)
            int kb = (f & 63) >> 1;                  // k element offset
            const unsigned short* ga = A  + (size_t)(m0 + row) * K + kk + kb;
            const unsigned short* gb = Bw + (size_t)(n0 + row) * K + kk + kb;
            unsigned short* la = lA + ((r * 4096 + wid * 1024) >> 1);  // wave-uniform
            unsigned short* lb = lB + ((r * 4096 + wid * 1024) >> 1);
            __builtin_amdgcn_global_load_lds((const __attribute__((address_space(1))) void*)ga,
                                             (__attribute__((address_space(3))) void*)la, 16, 0, 0);
            __builtin_amdgcn_global_load_lds((const __attribute__((address_space(1))) void*)gb,
                                             (__attribute__((address_space(3))) void*)lb, 16, 0, 0);
        }
        __syncthreads();
        bf16x8 af[4];
        #pragma unroll
        for (int i = 0; i < 4; ++i)
            af[i] = *(const bf16x8*)(lA + (wr + i * 16 + (lane & 15)) * 32 + (lane >> 4) * 8);
        #pragma unroll
        for (int j = 0; j < 4; ++j) {
            bf16x8 bfr = *(const bf16x8*)(lB + (wc + j * 16 + (lane & 15)) * 32 + (lane >> 4) * 8);
            #pragma unroll
            for (int i = 0; i < 4; ++i)
                acc[i][j] = __builtin_amdgcn_mfma_f32_16x16x32_bf16(af[i], bfr, acc[i][j], 0, 0, 0);
        }
        __syncthreads();
    }

    int cl = lane & 15, rb = (lane >> 4) * 4;
    #pragma unroll
    for (int i = 0; i < 4; ++i) {
        #pragma unroll
        for (int j = 0; j < 4; ++j) {
            #pragma unroll
            for (int r = 0; r < 4; ++r) {
                int row = m0 + wr + i * 16 + rb + r;
                int col = n0 + wc + j * 16 + cl;
                float v = acc[i][j][r] + bias[col];
                if (EPI == 0) {
                    outF[(size_t)row * N + col] = v;
                } else if (EPI == 2) {
                    float t = tanhf(0.7978845608f * (v + 0.044715f * v * v * v));
                    outH[(size_t)row * N + col] = f2bf(0.5f * v * (1.f + t));
                } else {
                    int b = row >> 10;
                    float gt = ada[b * 6144 + gate_off + col];
                    outF[(size_t)row * N + col] = resid[(size_t)row * N + col] + gt * v;
                }
            }
        }
    }
}

// ---------------- q/k rms-norm in place on fp32 qkv ----------------
// row = 64 contiguous floats; one wave per row; grid 65536, block 256
__global__ void k_qknorm(float* __restrict__ qkv, const float* __restrict__ gq,
                         const float* __restrict__ gk) {
    int rid = blockIdx.x * 4 + (threadIdx.x >> 6);
    int lane = threadIdx.x & 63;
    int m = rid >> 5;            // 0..8191 (b*1024+t)
    int h = (rid >> 1) & 15;
    int s = rid & 1;             // 0=q, 1=k
    float* p = qkv + (size_t)m * 3072 + s * 1024 + h * 64;
    float v = p[lane];
    float ss = v * v;
    #pragma unroll
    for (int o = 32; o; o >>= 1) ss += __shfl_xor(ss, o);
    float nrm = fmaxf(sqrtf(ss), 1e-12f);
    // q: rmsnorm*hd^-0.5 -> gq/||q||;  k: rmsnorm -> 8*gk/||k||
    float f = (s == 0 ? gq[0] : 8.f * gk[0]) / nrm;
    p[lane] = v * f;
}

// ---------------- attention: thread-per-query-row, fp32 ----------------
// scores bounded by |8*gq*gk| -> single-pass exp-sum without max tracking
// grid (B*H=128, T/256=4), block 256
__global__ __launch_bounds__(256)
void k_attn(const float* __restrict__ qkv, unsigned short* __restrict__ outp) {
    __shared__ float Kt[64][64];
    __shared__ float Vt[64][64];
    int bh = blockIdx.x;
    int b = bh >> 4, h = bh & 15;
    int t = blockIdx.y * 256 + threadIdx.x;
    size_t qbase = ((size_t)(b * 1024 + t)) * 3072 + h * 64;
    float q[64];
    #pragma unroll
    for (int i = 0; i < 16; ++i) {
        float4 v = *(const float4*)(qkv + qbase + i * 4);
        q[i * 4 + 0] = v.x; q[i * 4 + 1] = v.y; q[i * 4 + 2] = v.z; q[i * 4 + 3] = v.w;
    }
    float acc[64] = {};
    float den = 0.f;
    for (int kt = 0; kt < 16; ++kt) {
        __syncthreads();
        #pragma unroll
        for (int i = 0; i < 4; ++i) {
            int fid = i * 256 + threadIdx.x;
            int row = fid >> 4, c4 = (fid & 15) * 4;
            size_t src = ((size_t)(b * 1024 + kt * 64 + row)) * 3072 + 1024 + h * 64 + c4;
            *(float4*)(&Kt[row][c4]) = *(const float4*)(qkv + src);
            *(float4*)(&Vt[row][c4]) = *(const float4*)(qkv + src + 1024);
        }
        __syncthreads();
        for (int j = 0; j < 64; ++j) {
            const float4* kr = (const float4*)(&Kt[j][0]);
            float s = 0.f;
            #pragma unroll
            for (int u = 0; u < 16; ++u) {
                float4 kv = kr[u];
                s += q[u * 4 + 0] * kv.x + q[u * 4 + 1] * kv.y + q[u * 4 + 2] * kv.z + q[u * 4 + 3] * kv.w;
            }
            float p = __expf(s);
            den += p;
            const float4* vr = (const float4*)(&Vt[j][0]);
            #pragma unroll
            for (int u = 0; u < 16; ++u) {
                float4 vv = vr[u];
                acc[u * 4 + 0] += p * vv.x; acc[u * 4 + 1] += p * vv.y;
                acc[u * 4 + 2] += p * vv.z; acc[u * 4 + 3] += p * vv.w;
            }
        }
    }
    float inv = 1.f / den;
    size_t ob = ((size_t)(b * 1024 + t)) * 1024 + h * 64;
    #pragma unroll
    for (int gI = 0; gI < 8; ++gI) {
        uint4 u;
        unsigned* pu = (unsigned*)&u;
        #pragma unroll
        for (int w = 0; w < 4; ++w) {
            unsigned lo = f2bf(acc[gI * 8 + w * 2] * inv);
            unsigned hi = f2bf(acc[gI * 8 + w * 2 + 1] * inv);
            pu[w] = lo | (hi << 16);
        }
        *(uint4*)(outp + ob + gI * 8) = u;
    }
}

extern "C" void kernel_launch(void* const* d_in, const int* in_sizes, int n_in,
                              void* d_out, int out_size, void* d_ws, size_t ws_size,
                              hipStream_t stream) {
    const float* x     = (const float*)d_in[0];
    const float* c     = (const float*)d_in[1];
    const float* g1    = (const float*)d_in[2];
    const float* g2    = (const float*)d_in[3];
    const float* gq    = (const float*)d_in[4];
    const float* gk    = (const float*)d_in[5];
    const float* Wqkv  = (const float*)d_in[6];
    const float* bqkv  = (const float*)d_in[7];
    const float* Wproj = (const float*)d_in[8];
    const float* bproj = (const float*)d_in[9];
    const float* Wfc1  = (const float*)d_in[10];
    const float* bfc1  = (const float*)d_in[11];
    const float* Wfc2  = (const float*)d_in[12];
    const float* bfc2  = (const float*)d_in[13];
    const float* Wada  = (const float*)d_in[14];
    const float* bada  = (const float*)d_in[15];
    float* out = (float*)d_out;

    char* ws = (char*)d_ws;
    unsigned short* wqkv_bf = (unsigned short*)ws; ws += (size_t)3072 * 1024 * 2;
    unsigned short* wproj_bf= (unsigned short*)ws; ws += (size_t)1024 * 1024 * 2;
    unsigned short* wfc1_bf = (unsigned short*)ws; ws += (size_t)4096 * 1024 * 2;
    unsigned short* wfc2_bf = (unsigned short*)ws; ws += (size_t)4096 * 1024 * 2;
    float* ada = (float*)ws;                       ws += (size_t)8 * 6144 * 4;
    unsigned short* hbuf = (unsigned short*)ws;    ws += (size_t)8192 * 1024 * 2;  // h / o / h2
    float* qkvb = (float*)ws;                      // qkv fp32 (96MB) then fc1out bf16 (64MB)
    unsigned short* fc1out = (unsigned short*)qkvb;

    // 1) weight converts
    k_cvt<<<3072 * 1024 / 1024, 256, 0, stream>>>(Wqkv,  wqkv_bf);
    k_cvt<<<1024 * 1024 / 1024, 256, 0, stream>>>(Wproj, wproj_bf);
    k_cvt<<<4096 * 1024 / 1024, 256, 0, stream>>>(Wfc1,  wfc1_bf);
    k_cvt<<<4096 * 1024 / 1024, 256, 0, stream>>>(Wfc2,  wfc2_bf);
    // 2) adaLN
    k_ada<<<dim3(8, 1536), 256, 0, stream>>>(c, Wada, bada, ada);
    // 3) h = modulate(rmsnorm(x), scale_msa, shift_msa)
    k_norm_mod<<<8192, 256, 0, stream>>>(x, ada, g1, hbuf, 0, 1024);
    // 4) qkv = h @ Wqkv^T + bqkv  (fp32 out)
    k_gemm<0><<<dim3(64, 24), 256, 0, stream>>>(hbuf, wqkv_bf, bqkv, 3072, 1024,
                                                qkvb, nullptr, nullptr, nullptr, 0);
    // 5) q/k norms in place
    k_qknorm<<<65536, 256, 0, stream>>>(qkvb, gq, gk);
    // 6) attention -> o (bf16, reuse hbuf)
    k_attn<<<dim3(128, 4), 256, 0, stream>>>(qkvb, hbuf);
    // 7) x1 = x + gate_msa * (o @ Wproj^T + bproj)  -> d_out
    k_gemm<1><<<dim3(64, 8), 256, 0, stream>>>(hbuf, wproj_bf, bproj, 1024, 1024,
                                               out, nullptr, x, ada, 2048);
    // 8) h2 = modulate(rmsnorm(x1), scale_mlp, shift_mlp)
    k_norm_mod<<<8192, 256, 0, stream>>>(out, ada, g2, hbuf, 3072, 4096);
    // 9) fc1 + gelu -> bf16 (reuse qkv region)
    k_gemm<2><<<dim3(64, 32), 256, 0, stream>>>(hbuf, wfc1_bf, bfc1, 4096, 1024,
                                                nullptr, fc1out, nullptr, nullptr, 0);
    // 10) out = x1 + gate_mlp * (fc1out @ Wfc2^T + bfc2)
    k_gemm<3><<<dim3(64, 8), 256, 0, stream>>>(fc1out, wfc2_bf, bfc2, 1024, 4096,
                                               out, nullptr, out, ada, 5120);
}

// Round 2
// 464.960 us; speedup vs baseline: 3.3657x; 3.3657x over previous
//
#include <hip/hip_runtime.h>
#include <hip/hip_bf16.h>
#include <math.h>

typedef __bf16 bf16x8 __attribute__((ext_vector_type(8)));
typedef __bf16 bf16x4 __attribute__((ext_vector_type(4)));
typedef float  f32x4  __attribute__((ext_vector_type(4)));

#define DEV static __device__ __forceinline__

DEV unsigned short f2bf(float f) {
    unsigned u = __builtin_bit_cast(unsigned, f);
    u += 0x7fffu + ((u >> 16) & 1u);     // RNE
    return (unsigned short)(u >> 16);
}
DEV float bf2f(unsigned short u) {
    unsigned x = ((unsigned)u) << 16;
    return __builtin_bit_cast(float, x);
}

// ---------------- fp32 -> bf16 weight convert ----------------
__global__ void k_cvt(const float* __restrict__ in, unsigned short* __restrict__ out) {
    int i = (blockIdx.x * 256 + threadIdx.x) * 4;
    float4 v = *(const float4*)(in + i);
    ushort4 o;
    o.x = f2bf(v.x); o.y = f2bf(v.y); o.z = f2bf(v.z); o.w = f2bf(v.w);
    *(ushort4*)(out + i) = o;
}

// ---------------- adaLN: ada = silu(c) @ Wada^T + bada ----------------
__global__ void k_ada(const float* __restrict__ c, const float* __restrict__ Wada,
                      const float* __restrict__ bada, float* __restrict__ ada) {
    __shared__ float sc[1024];
    int b = blockIdx.x;
    int tid = threadIdx.x;
    for (int k = tid; k < 1024; k += 256) {
        float x = c[b * 1024 + k];
        sc[k] = x / (1.f + __expf(-x));
    }
    __syncthreads();
    int wid = tid >> 6, lane = tid & 63;
    int n = blockIdx.y * 4 + wid;
    const float* wr = Wada + (size_t)n * 1024;
    float acc = 0.f;
    #pragma unroll
    for (int k = 0; k < 1024; k += 64) acc += sc[k + lane] * wr[k + lane];
    #pragma unroll
    for (int o = 32; o; o >>= 1) acc += __shfl_xor(acc, o);
    if (lane == 0) ada[b * 6144 + n] = acc + bada[n];
}

// ---------------- fused rmsnorm + modulate -> bf16 ----------------
__global__ void k_norm_mod(const float* __restrict__ x, const float* __restrict__ ada,
                           const float* __restrict__ g, unsigned short* __restrict__ h,
                           int shift_off, int scale_off) {
    int row = blockIdx.x;
    int b = row >> 10;
    int tid = threadIdx.x;
    float4 v = *(const float4*)(x + (size_t)row * 1024 + tid * 4);
    float ss = v.x * v.x + v.y * v.y + v.z * v.z + v.w * v.w;
    #pragma unroll
    for (int o = 32; o; o >>= 1) ss += __shfl_xor(ss, o);
    __shared__ float red[4];
    int wid = tid >> 6, lane = tid & 63;
    if (lane == 0) red[wid] = ss;
    __syncthreads();
    float nrm = sqrtf(red[0] + red[1] + red[2] + red[3]);
    float f = g[0] * 32.f / fmaxf(nrm, 1e-12f);
    float4 s4 = *(const float4*)(ada + b * 6144 + scale_off + tid * 4);
    float4 h4 = *(const float4*)(ada + b * 6144 + shift_off + tid * 4);
    ushort4 o;
    o.x = f2bf(v.x * f * (1.f + s4.x) + h4.x);
    o.y = f2bf(v.y * f * (1.f + s4.y) + h4.y);
    o.z = f2bf(v.z * f * (1.f + s4.z) + h4.z);
    o.w = f2bf(v.w * f * (1.f + s4.w) + h4.w);
    *(ushort4*)(h + (size_t)row * 1024 + tid * 4) = o;
}

// ---------------- bf16 GEMM: C[m,n] = sum_k A[m,k]*B[n,k] (+epilogue) ----------------
// EPI: 0 = +bias -> bf16 (qkv)
//      1 = resid + gate*( +bias ) -> fp32 (proj -> x1)
//      2 = gelu_tanh( +bias )     -> bf16 (fc1)
//      3 = resid + gate*( +bias ) -> fp32 (fc2 -> out)
template <int EPI>
__global__ __launch_bounds__(256)
void k_gemm(const unsigned short* __restrict__ A, const unsigned short* __restrict__ Bw,
            const float* __restrict__ bias, int N, int K,
            float* __restrict__ outF, unsigned short* __restrict__ outH,
            const float* __restrict__ resid, const float* __restrict__ ada, int gate_off) {
    __shared__ unsigned short lA[128 * 32];
    __shared__ unsigned short lB[128 * 32];
    int tid = threadIdx.x;
    int m0 = blockIdx.x * 128, n0 = blockIdx.y * 128;
    int wid = tid >> 6, lane = tid & 63;
    int wr = (wid >> 1) * 64, wc = (wid & 1) * 64;
    f32x4 acc[4][4] = {};

    for (int kk = 0; kk < K; kk += 32) {
        #pragma unroll
        for (int r = 0; r < 2; ++r) {
            int f = r * 4096 + tid * 16;
            int row = f >> 6;
            int kb = (f & 63) >> 1;
            const unsigned short* ga = A  + (size_t)(m0 + row) * K + kk + kb;
            const unsigned short* gb = Bw + (size_t)(n0 + row) * K + kk + kb;
            unsigned short* la = lA + ((r * 4096 + wid * 1024) >> 1);
            unsigned short* lb = lB + ((r * 4096 + wid * 1024) >> 1);
            __builtin_amdgcn_global_load_lds((const __attribute__((address_space(1))) void*)ga,
                                             (__attribute__((address_space(3))) void*)la, 16, 0, 0);
            __builtin_amdgcn_global_load_lds((const __attribute__((address_space(1))) void*)gb,
                                             (__attribute__((address_space(3))) void*)lb, 16, 0, 0);
        }
        __syncthreads();
        bf16x8 af[4];
        #pragma unroll
        for (int i = 0; i < 4; ++i)
            af[i] = *(const bf16x8*)(lA + (wr + i * 16 + (lane & 15)) * 32 + (lane >> 4) * 8);
        #pragma unroll
        for (int j = 0; j < 4; ++j) {
            bf16x8 bfr = *(const bf16x8*)(lB + (wc + j * 16 + (lane & 15)) * 32 + (lane >> 4) * 8);
            #pragma unroll
            for (int i = 0; i < 4; ++i)
                acc[i][j] = __builtin_amdgcn_mfma_f32_16x16x32_bf16(af[i], bfr, acc[i][j], 0, 0, 0);
        }
        __syncthreads();
    }

    int cl = lane & 15, rb = (lane >> 4) * 4;
    #pragma unroll
    for (int i = 0; i < 4; ++i) {
        #pragma unroll
        for (int j = 0; j < 4; ++j) {
            #pragma unroll
            for (int r = 0; r < 4; ++r) {
                int row = m0 + wr + i * 16 + rb + r;
                int col = n0 + wc + j * 16 + cl;
                float v = acc[i][j][r] + bias[col];
                if (EPI == 0) {
                    outH[(size_t)row * N + col] = f2bf(v);
                } else if (EPI == 2) {
                    float t = tanhf(0.7978845608f * (v + 0.044715f * v * v * v));
                    outH[(size_t)row * N + col] = f2bf(0.5f * v * (1.f + t));
                } else {
                    int b = row >> 10;
                    float gt = ada[b * 6144 + gate_off + col];
                    outF[(size_t)row * N + col] = resid[(size_t)row * N + col] + gt * v;
                }
            }
        }
    }
}

// ---------------- qkv post: q/k rms-norm -> Qb/Kb bf16; V -> Vt [B,H,64,T] ----------------
// grid (B*H=128, T/64=16), block 256; thread: row = tid>>2 (64 rows), part = tid&3 (16 elems)
__global__ __launch_bounds__(256)
void k_qkv_post(const unsigned short* __restrict__ qkv,   // [8192][3072] bf16
                const float* __restrict__ gq, const float* __restrict__ gk,
                unsigned short* __restrict__ Qb, unsigned short* __restrict__ Kb,
                unsigned short* __restrict__ Vtg) {
    __shared__ unsigned short vt[64 * 72];   // [d][t], stride 72 (16B-aligned rows)
    int bh = blockIdx.x;
    int b = bh >> 4, h = bh & 15;
    int t0 = blockIdx.y * 64;
    int tid = threadIdx.x;
    int row = tid >> 2, part = tid & 3;
    size_t rbase = ((size_t)(b * 1024 + t0 + row)) * 3072 + h * 64 + part * 16;
    size_t obase = (size_t)bh * 65536 + (size_t)(t0 + row) * 64 + part * 16;

    #pragma unroll
    for (int s = 0; s < 2; ++s) {   // 0 = q, 1 = k
        uint4 u0 = *(const uint4*)(qkv + rbase + s * 1024);
        uint4 u1 = *(const uint4*)(qkv + rbase + s * 1024 + 8);
        float vals[16];
        const unsigned* pu = (const unsigned*)&u0;
        #pragma unroll
        for (int j = 0; j < 4; ++j) {
            vals[2*j]   = bf2f((unsigned short)(pu[j] & 0xffff));
            vals[2*j+1] = bf2f((unsigned short)(pu[j] >> 16));
        }
        pu = (const unsigned*)&u1;
        #pragma unroll
        for (int j = 0; j < 4; ++j) {
            vals[8+2*j]   = bf2f((unsigned short)(pu[j] & 0xffff));
            vals[8+2*j+1] = bf2f((unsigned short)(pu[j] >> 16));
        }
        float ss = 0.f;
        #pragma unroll
        for (int j = 0; j < 16; ++j) ss += vals[j] * vals[j];
        ss += __shfl_xor(ss, 1);
        ss += __shfl_xor(ss, 2);
        float nrm = fmaxf(sqrtf(ss), 1e-12f);
        float fsc = (s == 0 ? gq[0] : 8.f * gk[0]) / nrm;
        uint4 w0, w1;
        unsigned* pw = (unsigned*)&w0;
        #pragma unroll
        for (int j = 0; j < 4; ++j)
            pw[j] = (unsigned)f2bf(vals[2*j] * fsc) | ((unsigned)f2bf(vals[2*j+1] * fsc) << 16);
        pw = (unsigned*)&w1;
        #pragma unroll
        for (int j = 0; j < 4; ++j)
            pw[j] = (unsigned)f2bf(vals[8+2*j] * fsc) | ((unsigned)f2bf(vals[8+2*j+1] * fsc) << 16);
        unsigned short* dst = (s == 0 ? Qb : Kb);
        *(uint4*)(dst + obase)     = w0;
        *(uint4*)(dst + obase + 8) = w1;
    }
    // v: transpose in LDS
    {
        uint4 u0 = *(const uint4*)(qkv + rbase + 2048);
        uint4 u1 = *(const uint4*)(qkv + rbase + 2048 + 8);
        const unsigned* pu = (const unsigned*)&u0;
        #pragma unroll
        for (int j = 0; j < 4; ++j) {
            vt[(part * 16 + 2*j)     * 72 + row] = (unsigned short)(pu[j] & 0xffff);
            vt[(part * 16 + 2*j + 1) * 72 + row] = (unsigned short)(pu[j] >> 16);
        }
        pu = (const unsigned*)&u1;
        #pragma unroll
        for (int j = 0; j < 4; ++j) {
            vt[(part * 16 + 8 + 2*j)     * 72 + row] = (unsigned short)(pu[j] & 0xffff);
            vt[(part * 16 + 8 + 2*j + 1) * 72 + row] = (unsigned short)(pu[j] >> 16);
        }
    }
    __syncthreads();
    {
        int d = tid >> 2, seg = tid & 3;
        uint4 w0 = *(const uint4*)(vt + d * 72 + seg * 16);
        uint4 w1 = *(const uint4*)(vt + d * 72 + seg * 16 + 8);
        size_t vdst = (size_t)bh * 65536 + (size_t)d * 1024 + t0 + seg * 16;
        *(uint4*)(Vtg + vdst)     = w0;
        *(uint4*)(Vtg + vdst + 8) = w1;
    }
}

// ---------------- MFMA attention ----------------
// grid (B*H=128, T/64=16), block 256 (4 waves x 16 q-rows).
// S^T = mfma(K, Q): lane holds S[kk = 16f + 4*lg + r][m = m0 + li];
// exp'd fragments repack into PV A-frags with pi(g,j) = (j<4 ? 4g+j : 16+4g+j-4);
// V^T LDS reads use the same permutation (two ds_read_b64 per fragment).
__global__ __launch_bounds__(256)
void k_attn_mfma(const unsigned short* __restrict__ Qb,
                 const unsigned short* __restrict__ Kb,
                 const unsigned short* __restrict__ Vtg,
                 unsigned short* __restrict__ outp) {
    __shared__ unsigned short Kt[128 * 64];   // swizzled: 16B-granule col16 ^= (row&7)
    __shared__ unsigned short Vl[64 * 136];   // [d][k], stride 136 (pad 8)
    int bh = blockIdx.x;
    int t0 = blockIdx.y * 64;
    int tid = threadIdx.x, wid = tid >> 6, lane = tid & 63;
    int li = lane & 15, lg = lane >> 4;
    const size_t bh64k = (size_t)bh * 65536;

    bf16x8 q0, q1;
    {
        const unsigned short* Qg = Qb + bh64k + (size_t)(t0 + wid * 16 + li) * 64 + lg * 8;
        q0 = *(const bf16x8*)Qg;
        q1 = *(const bf16x8*)(Qg + 32);
    }
    f32x4 oacc[4] = {};
    float den = 0.f;

    for (int kt = 0; kt < 8; ++kt) {
        __syncthreads();   // previous tile's compute done before overwrite
        // stage K: global_load_lds, pre-swizzled source
        #pragma unroll
        for (int i = 0; i < 4; ++i) {
            int s = i * 256 + tid;
            int r = s >> 3, c16 = s & 7;
            const unsigned short* src = Kb + bh64k + (size_t)(kt * 128 + r) * 64 + ((c16 ^ (r & 7)) * 8);
            unsigned short* dst = Kt + i * 2048 + wid * 512;   // wave-uniform base
            __builtin_amdgcn_global_load_lds((const __attribute__((address_space(1))) void*)src,
                                             (__attribute__((address_space(3))) void*)dst, 16, 0, 0);
        }
        // stage V^T: reg-staged into padded rows
        #pragma unroll
        for (int i = 0; i < 4; ++i) {
            int s = i * 256 + tid;
            int d = s >> 4, k16 = s & 15;
            uint4 v = *(const uint4*)(Vtg + bh64k + (size_t)d * 1024 + kt * 128 + k16 * 8);
            *(uint4*)(Vl + d * 136 + k16 * 8) = v;
        }
        __syncthreads();

        // S^T = K . Q^T (16 MFMA), exp, den accumulation
        f32x4 st[8];
        #pragma unroll
        for (int f = 0; f < 8; ++f) {
            int row = f * 16 + li;
            bf16x8 a0 = *(const bf16x8*)(Kt + row * 64 + ((lg       ^ (row & 7)) * 8));
            bf16x8 a1 = *(const bf16x8*)(Kt + row * 64 + (((4 + lg) ^ (row & 7)) * 8));
            f32x4 s = {};
            s = __builtin_amdgcn_mfma_f32_16x16x32_bf16(a0, q0, s, 0, 0, 0);
            s = __builtin_amdgcn_mfma_f32_16x16x32_bf16(a1, q1, s, 0, 0, 0);
            f32x4 e;
            e[0] = __expf(s[0]); e[1] = __expf(s[1]);
            e[2] = __expf(s[2]); e[3] = __expf(s[3]);
            den += e[0] + e[1] + e[2] + e[3];
            st[f] = e;
        }
        // pack P -> A-frags; PV (16 MFMA)
        #pragma unroll
        for (int ks = 0; ks < 4; ++ks) {
            f32x4 e0 = st[2 * ks], e1 = st[2 * ks + 1];
            bf16x8 pa;
            pa[0] = (__bf16)e0[0]; pa[1] = (__bf16)e0[1]; pa[2] = (__bf16)e0[2]; pa[3] = (__bf16)e0[3];
            pa[4] = (__bf16)e1[0]; pa[5] = (__bf16)e1[1]; pa[6] = (__bf16)e1[2]; pa[7] = (__bf16)e1[3];
            #pragma unroll
            for (int df = 0; df < 4; ++df) {
                const unsigned short* vp = Vl + (df * 16 + li) * 136 + ks * 32 + lg * 4;
                bf16x4 v0 = *(const bf16x4*)vp;
                bf16x4 v1 = *(const bf16x4*)(vp + 16);
                bf16x8 vb = __builtin_shufflevector(v0, v1, 0, 1, 2, 3, 4, 5, 6, 7);
                oacc[df] = __builtin_amdgcn_mfma_f32_16x16x32_bf16(pa, vb, oacc[df], 0, 0, 0);
            }
        }
    }
    // full row-denominator: reduce across the four 16-lane groups
    den += __shfl_xor(den, 16);
    den += __shfl_xor(den, 32);

    int b = bh >> 4, h = bh & 15;
    #pragma unroll
    for (int r2 = 0; r2 < 4; ++r2) {
        float dm = __shfl(den, lg * 4 + r2);   // den for m = lg*4 + r2
        float inv = 1.f / dm;
        int t = t0 + wid * 16 + lg * 4 + r2;
        #pragma unroll
        for (int df = 0; df < 4; ++df) {
            int col = h * 64 + df * 16 + li;
            outp[((size_t)(b * 1024 + t)) * 1024 + col] = f2bf(oacc[df][r2] * inv);
        }
    }
}

extern "C" void kernel_launch(void* const* d_in, const int* in_sizes, int n_in,
                              void* d_out, int out_size, void* d_ws, size_t ws_size,
                              hipStream_t stream) {
    const float* x     = (const float*)d_in[0];
    const float* c     = (const float*)d_in[1];
    const float* g1    = (const float*)d_in[2];
    const float* g2    = (const float*)d_in[3];
    const float* gq    = (const float*)d_in[4];
    const float* gk    = (const float*)d_in[5];
    const float* Wqkv  = (const float*)d_in[6];
    const float* bqkv  = (const float*)d_in[7];
    const float* Wproj = (const float*)d_in[8];
    const float* bproj = (const float*)d_in[9];
    const float* Wfc1  = (const float*)d_in[10];
    const float* bfc1  = (const float*)d_in[11];
    const float* Wfc2  = (const float*)d_in[12];
    const float* bfc2  = (const float*)d_in[13];
    const float* Wada  = (const float*)d_in[14];
    const float* bada  = (const float*)d_in[15];
    float* out = (float*)d_out;

    char* ws = (char*)d_ws;
    unsigned short* wqkv_bf = (unsigned short*)ws; ws += (size_t)3072 * 1024 * 2;
    unsigned short* wproj_bf= (unsigned short*)ws; ws += (size_t)1024 * 1024 * 2;
    unsigned short* wfc1_bf = (unsigned short*)ws; ws += (size_t)4096 * 1024 * 2;
    unsigned short* wfc2_bf = (unsigned short*)ws; ws += (size_t)4096 * 1024 * 2;
    float* ada = (float*)ws;                       ws += (size_t)8 * 6144 * 4;
    unsigned short* hbuf = (unsigned short*)ws;    ws += (size_t)8192 * 1024 * 2;   // h / o / h2
    unsigned short* qkvb16 = (unsigned short*)ws;  ws += (size_t)8192 * 3072 * 2;   // bf16 qkv
    unsigned short* Qb  = (unsigned short*)ws;     ws += (size_t)8192 * 64 * 16 * 2;
    unsigned short* Kb  = (unsigned short*)ws;     ws += (size_t)8192 * 64 * 16 * 2;
    unsigned short* Vtg = (unsigned short*)ws;     ws += (size_t)8192 * 64 * 16 * 2;
    unsigned short* fc1out = qkvb16;               // reuse (qkv/Qb dead by fc1): 67.1MB >= 64MB

    // 1) weight converts
    k_cvt<<<3072 * 1024 / 1024, 256, 0, stream>>>(Wqkv,  wqkv_bf);
    k_cvt<<<1024 * 1024 / 1024, 256, 0, stream>>>(Wproj, wproj_bf);
    k_cvt<<<4096 * 1024 / 1024, 256, 0, stream>>>(Wfc1,  wfc1_bf);
    k_cvt<<<4096 * 1024 / 1024, 256, 0, stream>>>(Wfc2,  wfc2_bf);
    // 2) adaLN
    k_ada<<<dim3(8, 1536), 256, 0, stream>>>(c, Wada, bada, ada);
    // 3) h = modulate(rmsnorm(x), scale_msa, shift_msa)
    k_norm_mod<<<8192, 256, 0, stream>>>(x, ada, g1, hbuf, 0, 1024);
    // 4) qkv = h @ Wqkv^T + bqkv  (bf16 out)
    k_gemm<0><<<dim3(64, 24), 256, 0, stream>>>(hbuf, wqkv_bf, bqkv, 3072, 1024,
                                                nullptr, qkvb16, nullptr, nullptr, 0);
    // 5) q/k norm + V transpose
    k_qkv_post<<<dim3(128, 16), 256, 0, stream>>>(qkvb16, gq, gk, Qb, Kb, Vtg);
    // 6) MFMA attention -> o (bf16, reuse hbuf)
    k_attn_mfma<<<dim3(128, 16), 256, 0, stream>>>(Qb, Kb, Vtg, hbuf);
    // 7) x1 = x + gate_msa * (o @ Wproj^T + bproj)  -> d_out
    k_gemm<1><<<dim3(64, 8), 256, 0, stream>>>(hbuf, wproj_bf, bproj, 1024, 1024,
                                               out, nullptr, x, ada, 2048);
    // 8) h2 = modulate(rmsnorm(x1), scale_mlp, shift_mlp)
    k_norm_mod<<<8192, 256, 0, stream>>>(out, ada, g2, hbuf, 3072, 4096);
    // 9) fc1 + gelu -> bf16
    k_gemm<2><<<dim3(64, 32), 256, 0, stream>>>(hbuf, wfc1_bf, bfc1, 4096, 1024,
                                                nullptr, fc1out, nullptr, nullptr, 0);
    // 10) out = x1 + gate_mlp * (fc1out @ Wfc2^T + bfc2)
    k_gemm<3><<<dim3(64, 8), 256, 0, stream>>>(fc1out, wfc2_bf, bfc2, 1024, 4096,
                                               out, nullptr, out, ada, 5120);
}